// Round 14
// baseline (750.244 us; speedup 1.0000x reference)
//
#include <hip/hip_runtime.h>
#include <hip/hip_bf16.h>
#include <math.h>

// Problem constants
#define N_TRAIN 4096
#define N_FEAT  64
#define NHID    256
#define ENC     256
#define GH      256
#define AH      64
#define NANTES  32768
#define TSTEPS  32

#define SSTR 528   // lstm setup LDS row stride (f32)

typedef __attribute__((ext_vector_type(8))) short bf16x8;
typedef __attribute__((ext_vector_type(4))) float f32x4;

__device__ __forceinline__ float sigmoidf_(float x) {
    return 1.0f / (1.0f + __expf(-x));
}
__device__ __forceinline__ float tanhf_(float x) {
    return 1.0f - 2.0f / (__expf(2.0f * x) + 1.0f);
}
__device__ __forceinline__ unsigned short f2bf_rne(float x) {
    unsigned int u = __float_as_uint(x);
    unsigned int r = u + 0x7FFFu + ((u >> 16) & 1u);
    return (unsigned short)(r >> 16);
}
__device__ __forceinline__ float bf2f(unsigned short b) {
    return __uint_as_float(((unsigned int)b) << 16);
}

// ---------------------------------------------------------------------------
// Kernel 0: zero the e-sum accumulator
// ---------------------------------------------------------------------------
__global__ void zero_kernel(float* __restrict__ esum) {
    int tid = blockIdx.x * blockDim.x + threadIdx.x;
    for (int i = tid; i < TSTEPS * GH; i += gridDim.x * blockDim.x)
        esum[i] = 0.0f;
}

// ---------------------------------------------------------------------------
// Kernel P: pack Whh (1024x256 f32) into MFMA-fragment-ordered bf16 (hi only).
// ---------------------------------------------------------------------------
__global__ void pack_whh(const float* __restrict__ Whh,
                         unsigned short* __restrict__ hi)
{
    int g = blockIdx.x * 256 + threadIdx.x;      // 0 .. 32767
    if (g >= 64 * 8 * 64) return;
    int lane  = g & 63;
    int ks    = (g >> 6) & 7;
    int ntile = g >> 9;
    int n  = ntile * 16 + (lane & 15);
    int k0 = ks * 32 + (lane >> 4) * 8;
    const float* src = Whh + n * 256 + k0;
    #pragma unroll
    for (int j = 0; j < 8; ++j)
        hi[g * 8 + j] = f2bf_rne(src[j]);
}

// ---------------------------------------------------------------------------
// Kernel P2: pack attW1[:4096] (4096x64 f32, k-major) into MFMA B-fragment
// order, bf16 hi/lo.
// ---------------------------------------------------------------------------
__global__ void pack_wa(const float* __restrict__ attW1,
                        unsigned short* __restrict__ hi,
                        unsigned short* __restrict__ lo)
{
    int g = blockIdx.x * 256 + threadIdx.x;      // 0 .. 32767
    if (g >= 4 * 128 * 64) return;
    int lane = g & 63;
    int ks   = (g >> 6) & 127;
    int ct   = g >> 13;
    int n  = ct * 16 + (lane & 15);
    int k0 = ks * 32 + (lane >> 4) * 8;
    const float* src = attW1 + (size_t)k0 * AH + n;
    #pragma unroll
    for (int j = 0; j < 8; ++j) {
        float x = src[(size_t)j * AH];
        unsigned short h16 = f2bf_rne(x);
        hi[g * 8 + j] = h16;
        lo[g * 8 + j] = f2bf_rne(x - bf2f(h16));
    }
}

// ---------------------------------------------------------------------------
// Kernel A: fused encoder -> x_proj -> 32-step MFMA LSTM -> per-step h sums
// Grid: 256 blocks x 1024 threads (16 waves -> 4 waves/SIMD TLP).
// Wave w (0..15) owns hidden cols [w*16, w*16+16): one n-tile per gate.
// Per-wave live set ~85 VGPR (bA/bB 32 + acc 16 + xpf 16 + c 4 + temps)
// under the (1024,4) 128-reg cap -> no spills, clean R6-style schedule.
// 2-term bf16 split: h = hhi + hlo; Whh bf16-hi only.
// ---------------------------------------------------------------------------
__global__ __launch_bounds__(1024, 4) void lstm_kernel(
    const float* __restrict__ ctx,
    const float* __restrict__ encW1, const float* __restrict__ encb1,
    const float* __restrict__ encW2, const float* __restrict__ encb2,
    const float* __restrict__ Wih,
    const float* __restrict__ bih,  const float* __restrict__ bhh,
    const unsigned short* __restrict__ Wph,
    float* __restrict__ esum)
{
    __shared__ float sbuf[16 * SSTR];      // 33792 B setup scratch
    __shared__ short hhi[2][16 * 256];     // 16 KB, XOR-swizzled cols
    __shared__ short hlo[2][16 * 256];     // 16 KB

    const int tid   = threadIdx.x;
    const int j     = tid & 255;
    const int rh    = tid >> 8;       // 0..3
    const int rbase = rh * 4;
    const int r0    = blockIdx.x * 16;

    // hid = relu(ctx @ encW1 + b1) -> sbuf cols [0,256)
    {
        float acc[4];
        float b = encb1[j];
        #pragma unroll
        for (int r = 0; r < 4; ++r) acc[r] = b;
        for (int k = 0; k < N_FEAT; ++k) {
            float w = encW1[k * NHID + j];
            #pragma unroll
            for (int r = 0; r < 4; ++r)
                acc[r] = fmaf(ctx[(r0 + rbase + r) * N_FEAT + k], w, acc[r]);
        }
        #pragma unroll
        for (int r = 0; r < 4; ++r)
            sbuf[(rbase + r) * SSTR + j] = fmaxf(acc[r], 0.0f);
    }
    __syncthreads();

    // phi = hid @ encW2 + b2 -> sbuf cols [264,520)
    {
        float p[4];
        float b = encb2[j];
        #pragma unroll
        for (int r = 0; r < 4; ++r) p[r] = b;
        for (int k = 0; k < NHID; ++k) {
            float w = encW2[k * ENC + j];
            #pragma unroll
            for (int r = 0; r < 4; ++r)
                p[r] = fmaf(sbuf[(rbase + r) * SSTR + k], w, p[r]);
        }
        __syncthreads();
        #pragma unroll
        for (int r = 0; r < 4; ++r)
            sbuf[(rbase + r) * SSTR + 264 + j] = p[r];
    }
    __syncthreads();

    // xp[g][r] in registers (reads phi)
    float xp[4][4];
    #pragma unroll
    for (int g = 0; g < 4; ++g) {
        int m = g * 256 + j;
        float b = bih[m] + bhh[m];
        #pragma unroll
        for (int r = 0; r < 4; ++r) xp[g][r] = b;
        const float4* wrow = (const float4*)(Wih + m * ENC);
        for (int k4 = 0; k4 < ENC / 4; ++k4) {
            float4 wv = wrow[k4];
            #pragma unroll
            for (int r = 0; r < 4; ++r) {
                const float* ph = &sbuf[(rbase + r) * SSTR + 264 + k4 * 4];
                float v = xp[g][r];
                v = fmaf(ph[0], wv.x, v);
                v = fmaf(ph[1], wv.y, v);
                v = fmaf(ph[2], wv.z, v);
                v = fmaf(ph[3], wv.w, v);
                xp[g][r] = v;
            }
        }
    }
    __syncthreads();   // phi consumed

    const int w    = tid >> 6;        // wave 0..15
    const int l    = tid & 63;
    const int col  = l & 15;          // C col / A row
    const int kp   = l >> 4;          // 0..3
    const int arow = col;
    const int asw  = (arow & 7) << 3; // short-unit XOR swizzle

    // transfer xp -> C-fragment layout via sbuf cols [0,256), one gate at a time
    f32x4 xpf[4];
    #pragma unroll 1
    for (int g = 0; g < 4; ++g) {
        #pragma unroll
        for (int r = 0; r < 4; ++r)
            sbuf[(rbase + r) * SSTR + j] = xp[g][r];
        __syncthreads();
        #pragma unroll
        for (int q = 0; q < 4; ++q)
            xpf[g][q] = sbuf[(kp * 4 + q) * SSTR + w * 16 + col];
        __syncthreads();
    }

    for (int i = tid; i < 16 * 256; i += 1024) { hhi[0][i] = 0; hlo[0][i] = 0; }
    __syncthreads();

    const unsigned short* Bh = Wph + (size_t)l * 8;

    float c[4];
    #pragma unroll
    for (int q = 0; q < 4; ++q) c[q] = 0.0f;

// load B group (4 gates, ntile = g*16 + w) for ks_ into dst[4]
#define LOADB(dst, ks_) do {                                                 \
        _Pragma("unroll") for (int g = 0; g < 4; ++g)                        \
            dst[g] = *(const bf16x8*)(Bh +                                   \
                (size_t)(((g * 16 + w) * 8 + (ks_)) * 64) * 8);              \
    } while (0)

// 8 MFMAs for group ks_ consuming b_[4]
#define MFG(b_, ks_) do {                                                    \
        bf16x8 ah = *(const bf16x8*)&Ahi[arow * 256 +                        \
                        (((ks_) * 32 + kp * 8) ^ asw)];                      \
        bf16x8 al = *(const bf16x8*)&Alo[arow * 256 +                        \
                        (((ks_) * 32 + kp * 8) ^ asw)];                      \
        _Pragma("unroll") for (int g = 0; g < 4; ++g) {                      \
            acc[g] = __builtin_amdgcn_mfma_f32_16x16x32_bf16(al, b_[g], acc[g], 0, 0, 0); \
            acc[g] = __builtin_amdgcn_mfma_f32_16x16x32_bf16(ah, b_[g], acc[g], 0, 0, 0); \
        }                                                                    \
    } while (0)

    for (int t = 0; t < TSTEPS; ++t) {
        const short* Ahi = hhi[t & 1];
        const short* Alo = hlo[t & 1];
        short* Nhi = hhi[(t + 1) & 1];
        short* Nlo = hlo[(t + 1) & 1];

        f32x4 acc[4];
        #pragma unroll
        for (int g = 0; g < 4; ++g) acc[g] = xpf[g];

        bf16x8 bA[4], bB[4];
        LOADB(bA, 0); LOADB(bB, 1);
        MFG(bA, 0); LOADB(bA, 2);
        MFG(bB, 1); LOADB(bB, 3);
        MFG(bA, 2); LOADB(bA, 4);
        MFG(bB, 3); LOADB(bB, 5);
        MFG(bA, 4); LOADB(bA, 6);
        MFG(bB, 5); LOADB(bB, 7);
        MFG(bA, 6);
        MFG(bB, 7);

        // ---- pointwise (register resident) ----
        float s = 0.0f;
        #pragma unroll
        for (int q = 0; q < 4; ++q) {
            float iv = sigmoidf_(acc[0][q]);
            float fv = sigmoidf_(acc[1][q]);
            float gv = tanhf_   (acc[2][q]);
            float ov = sigmoidf_(acc[3][q]);
            c[q] = fv * c[q] + iv * gv;
            float hv = ov * tanhf_(c[q]);
            s += hv;
            unsigned short h16 = f2bf_rne(hv);
            float lof = hv - bf2f(h16);
            int row  = kp * 4 + q;
            int hcol = w * 16 + col;
            int sidx = row * 256 + (hcol ^ ((row & 7) << 3));
            Nhi[sidx] = (short)h16;
            Nlo[sidx] = (short)f2bf_rne(lof);
        }

        // e-sum: reduce over the 16 rows (kp groups share col)
        float v = s;
        v += __shfl_xor(v, 16);
        v += __shfl_xor(v, 32);
        if (l < 16)
            atomicAdd(&esum[t * GH + w * 16 + l], v);
        __syncthreads();
    }
#undef LOADB
#undef MFG
}

// ---------------------------------------------------------------------------
// Kernel C: proj[t][c] = (esum[t]/4096) @ W1_h + att_b1[c]
// ---------------------------------------------------------------------------
__global__ void proj_kernel(const float* __restrict__ esum,
                            const float* __restrict__ attW1,
                            const float* __restrict__ attb1,
                            float* __restrict__ proj)
{
    __shared__ float part[4][AH];
    const int t   = blockIdx.x;
    const int cix = threadIdx.x & 63;
    const int g   = threadIdx.x >> 6;
    float a = 0.0f;
    #pragma unroll 4
    for (int k = g * 64; k < g * 64 + 64; ++k) {
        float e = esum[t * GH + k] * (1.0f / (float)N_TRAIN);
        a = fmaf(e, attW1[(size_t)(N_TRAIN + k) * AH + cix], a);
    }
    part[g][cix] = a;
    __syncthreads();
    if (threadIdx.x < AH)
        proj[t * AH + cix] = part[0][cix] + part[1][cix] + part[2][cix] +
                             part[3][cix] + attb1[cix];
}

// ---------------------------------------------------------------------------
// Kernel D: S_proj via MFMA (4-term bf16 hi/lo split), fused scores epilogue.
// (unchanged from round 10)
// ---------------------------------------------------------------------------
__global__ __launch_bounds__(512, 4) void scores_kernel(
    const float* __restrict__ S,
    const unsigned short* __restrict__ Wah,
    const unsigned short* __restrict__ Wal,
    const float* __restrict__ proj,
    const float* __restrict__ attw2,
    const float* __restrict__ attb2,
    float* __restrict__ out)
{
    __shared__ float projl[TSTEPS * AH]; // 8 KB
    __shared__ float w2l[AH];

    const int tid   = threadIdx.x;
    const int wv    = tid >> 6;          // 0..7: ante-tile
    const int l     = tid & 63;
    const int kp    = l >> 4;            // 0..3
    const int atile = blockIdx.x * 128 + wv * 16;
    const int an    = atile + (l & 15);  // this lane's A-row (ante)

    f32x4 acc[4];
    #pragma unroll
    for (int ct = 0; ct < 4; ++ct) acc[ct] = (f32x4){0.f, 0.f, 0.f, 0.f};

    const float* Sp = S + an;
    const unsigned short* Bh = Wah + (size_t)l * 8;
    const unsigned short* Bl = Wal + (size_t)l * 8;

#define LOADS(dst, ks_) do {                                                 \
        _Pragma("unroll") for (int jj = 0; jj < 8; ++jj)                     \
            dst[jj] = Sp[(size_t)(32 * (ks_) + kp * 8 + jj) * NANTES];       \
    } while (0)

    float sA[8], sB[8];
    LOADS(sA, 0);
    LOADS(sB, 1);

    #pragma unroll 2
    for (int ks = 0; ks < 128; ++ks) {
        bf16x8 bh[4], bl[4];
        #pragma unroll
        for (int ct = 0; ct < 4; ++ct) {
            size_t off = (size_t)((ct * 128 + ks) * 64) * 8;
            bh[ct] = *(const bf16x8*)(Bh + off);
            bl[ct] = *(const bf16x8*)(Bl + off);
        }

        float* cur = (ks & 1) ? sB : sA;
        bf16x8 ah, al;
        #pragma unroll
        for (int jj = 0; jj < 8; ++jj) {
            float x = cur[jj];
            unsigned short h16 = f2bf_rne(x);
            ah[jj] = (short)h16;
            al[jj] = (short)f2bf_rne(x - bf2f(h16));
        }

        if (ks < 126) LOADS(cur, ks + 2);

        #pragma unroll
        for (int ct = 0; ct < 4; ++ct) {
            acc[ct] = __builtin_amdgcn_mfma_f32_16x16x32_bf16(al, bl[ct], acc[ct], 0, 0, 0);
            acc[ct] = __builtin_amdgcn_mfma_f32_16x16x32_bf16(al, bh[ct], acc[ct], 0, 0, 0);
            acc[ct] = __builtin_amdgcn_mfma_f32_16x16x32_bf16(ah, bl[ct], acc[ct], 0, 0, 0);
            acc[ct] = __builtin_amdgcn_mfma_f32_16x16x32_bf16(ah, bh[ct], acc[ct], 0, 0, 0);
        }
    }
#undef LOADS

    // ---- epilogue ----
    for (int i = tid; i < TSTEPS * AH; i += 512) projl[i] = proj[i];
    if (tid < AH) w2l[tid] = attw2[tid];
    __syncthreads();

    const float b2v = attb2[0];
    const int cn = l & 15;               // C col within tile
    #pragma unroll 1
    for (int t = 0; t < TSTEPS; ++t) {
        #pragma unroll
        for (int q = 0; q < 4; ++q) {
            float sc = 0.0f;
            #pragma unroll
            for (int ct = 0; ct < 4; ++ct) {
                int colg = ct * 16 + cn;
                sc += fmaxf(acc[ct][q] + projl[t * AH + colg], 0.0f) * w2l[colg];
            }
            sc += __shfl_xor(sc, 1);
            sc += __shfl_xor(sc, 2);
            sc += __shfl_xor(sc, 4);
            sc += __shfl_xor(sc, 8);
            if (cn == 0)
                out[(size_t)t * NANTES + atile + kp * 4 + q] = sc + b2v;
        }
    }
}

// ---------------------------------------------------------------------------
// Kernel E: per-step argmax (first-max semantics).
// ---------------------------------------------------------------------------
__global__ void argmax_kernel(const float* __restrict__ scores,
                              float* __restrict__ out)
{
    __shared__ float bv[256];
    __shared__ int   bidx[256];
    const int t = blockIdx.x, tid = threadIdx.x;
    float best = -INFINITY;
    int   bi   = 0x7fffffff;
    for (int a = tid; a < NANTES; a += 256) {
        float v = scores[(size_t)t * NANTES + a];
        if (v > best) { best = v; bi = a; }
    }
    bv[tid] = best; bidx[tid] = bi;
    __syncthreads();
    for (int s = 128; s > 0; s >>= 1) {
        if (tid < s) {
            if (bv[tid + s] > bv[tid] ||
                (bv[tid + s] == bv[tid] && bidx[tid + s] < bidx[tid])) {
                bv[tid] = bv[tid + s];
                bidx[tid] = bidx[tid + s];
            }
        }
        __syncthreads();
    }
    if (tid == 0)
        out[(size_t)TSTEPS * NANTES + t] = (float)bidx[0];
}

// ---------------------------------------------------------------------------
extern "C" void kernel_launch(void* const* d_in, const int* in_sizes, int n_in,
                              void* d_out, int out_size, void* d_ws, size_t ws_size,
                              hipStream_t stream)
{
    const float* ctx   = (const float*)d_in[0];
    const float* S     = (const float*)d_in[1];
    const float* encW1 = (const float*)d_in[2];
    const float* encb1 = (const float*)d_in[3];
    const float* encW2 = (const float*)d_in[4];
    const float* encb2 = (const float*)d_in[5];
    const float* Wih   = (const float*)d_in[6];
    const float* Whh   = (const float*)d_in[7];
    const float* bih   = (const float*)d_in[8];
    const float* bhh   = (const float*)d_in[9];
    const float* attW1 = (const float*)d_in[10];
    const float* attb1 = (const float*)d_in[11];
    const float* attw2 = (const float*)d_in[12];
    const float* attb2 = (const float*)d_in[13];

    char* ws = (char*)d_ws;
    float* esum = (float*)ws;                                     // 32 KB
    float* proj = (float*)(ws + 32768);                           // 8 KB
    unsigned short* Wph = (unsigned short*)(ws + 40960);          // 512 KB
    unsigned short* Wah = (unsigned short*)(ws + 40960 + 524288); // 512 KB
    unsigned short* Wal = (unsigned short*)(ws + 40960 + 1048576);// 512 KB
    float* out  = (float*)d_out;

    zero_kernel<<<dim3(8), dim3(256), 0, stream>>>(esum);
    pack_whh<<<dim3(128), dim3(256), 0, stream>>>(Whh, Wph);
    pack_wa<<<dim3(128), dim3(256), 0, stream>>>(attW1, Wah, Wal);
    lstm_kernel<<<dim3(N_TRAIN / 16), dim3(1024), 0, stream>>>(
        ctx, encW1, encb1, encW2, encb2, Wih, bih, bhh, Wph, esum);
    proj_kernel<<<dim3(TSTEPS), dim3(256), 0, stream>>>(esum, attW1, attb1, proj);
    scores_kernel<<<dim3(NANTES / 128), dim3(512), 0, stream>>>(
        S, Wah, Wal, proj, attw2, attb2, out);
    argmax_kernel<<<dim3(TSTEPS), dim3(256), 0, stream>>>(out, out);
}

// Round 15
// 583.841 us; speedup vs baseline: 1.2850x; 1.2850x over previous
//
#include <hip/hip_runtime.h>
#include <hip/hip_bf16.h>
#include <math.h>

// Problem constants
#define N_TRAIN 4096
#define N_FEAT  64
#define NHID    256
#define ENC     256
#define GH      256
#define AH      64
#define NANTES  32768
#define TSTEPS  32

#define SSTR 528   // lstm setup LDS row stride (f32)

typedef __attribute__((ext_vector_type(8))) short bf16x8;
typedef __attribute__((ext_vector_type(4))) float f32x4;

#define BMFMA(a_, b_, c_) __builtin_amdgcn_mfma_f32_16x16x32_bf16(a_, b_, c_, 0, 0, 0)

__device__ __forceinline__ float sigmoidf_(float x) {
    return 1.0f / (1.0f + __expf(-x));
}
__device__ __forceinline__ float tanhf_(float x) {
    return 1.0f - 2.0f / (__expf(2.0f * x) + 1.0f);
}
__device__ __forceinline__ unsigned short f2bf_rne(float x) {
    unsigned int u = __float_as_uint(x);
    unsigned int r = u + 0x7FFFu + ((u >> 16) & 1u);
    return (unsigned short)(r >> 16);
}
__device__ __forceinline__ float bf2f(unsigned short b) {
    return __uint_as_float(((unsigned int)b) << 16);
}

// async 16B/lane global -> LDS (wave-uniform LDS base, per-lane global src)
__device__ __forceinline__ void async16(const void* g, void* l) {
    __builtin_amdgcn_global_load_lds(
        (const __attribute__((address_space(1))) void*)g,
        (__attribute__((address_space(3))) void*)l, 16, 0, 0);
}

// ---------------------------------------------------------------------------
// Kernel 0: zero the e-sum accumulator
// ---------------------------------------------------------------------------
__global__ void zero_kernel(float* __restrict__ esum) {
    int tid = blockIdx.x * blockDim.x + threadIdx.x;
    for (int i = tid; i < TSTEPS * GH; i += gridDim.x * blockDim.x)
        esum[i] = 0.0f;
}

// ---------------------------------------------------------------------------
// Kernel P: pack Whh (1024x256 f32) into MFMA-fragment-ordered bf16 (hi only).
// ---------------------------------------------------------------------------
__global__ void pack_whh(const float* __restrict__ Whh,
                         unsigned short* __restrict__ hi)
{
    int g = blockIdx.x * 256 + threadIdx.x;      // 0 .. 32767
    if (g >= 64 * 8 * 64) return;
    int lane  = g & 63;
    int ks    = (g >> 6) & 7;
    int ntile = g >> 9;
    int n  = ntile * 16 + (lane & 15);
    int k0 = ks * 32 + (lane >> 4) * 8;
    const float* src = Whh + n * 256 + k0;
    #pragma unroll
    for (int j = 0; j < 8; ++j)
        hi[g * 8 + j] = f2bf_rne(src[j]);
}

// ---------------------------------------------------------------------------
// Kernel P2: pack attW1[:4096] (4096x64 f32, k-major) into MFMA B-fragment
// order, bf16 hi/lo.
// ---------------------------------------------------------------------------
__global__ void pack_wa(const float* __restrict__ attW1,
                        unsigned short* __restrict__ hi,
                        unsigned short* __restrict__ lo)
{
    int g = blockIdx.x * 256 + threadIdx.x;      // 0 .. 32767
    if (g >= 4 * 128 * 64) return;
    int lane = g & 63;
    int ks   = (g >> 6) & 127;
    int ct   = g >> 13;
    int n  = ct * 16 + (lane & 15);
    int k0 = ks * 32 + (lane >> 4) * 8;
    const float* src = attW1 + (size_t)k0 * AH + n;
    #pragma unroll
    for (int j = 0; j < 8; ++j) {
        float x = src[(size_t)j * AH];
        unsigned short h16 = f2bf_rne(x);
        hi[g * 8 + j] = h16;
        lo[g * 8 + j] = f2bf_rne(x - bf2f(h16));
    }
}

// ---------------------------------------------------------------------------
// Kernel A: fused encoder -> x_proj -> 32-step MFMA LSTM -> per-step h sums
// Grid: 256 blocks x 512 threads (8 waves), 1 block/CU.
// B-stream via ASYNC global_load_lds into a per-wave 3-slot x 4KB LDS ring
// (prefetch depth lives in LDS, not VGPRs -> no 128-reg wall). Counted
// s_waitcnt vmcnt(8) = 2 groups always in flight; FIFO issue ra->rb->rc;
// B is step-invariant so the pipeline runs CONTINUOUSLY across steps
// (raw s_barrier + lgkmcnt(0) only -- no vmcnt drain at the barrier).
// ---------------------------------------------------------------------------
__global__ __launch_bounds__(512, 2) void lstm_kernel(
    const float* __restrict__ ctx,
    const float* __restrict__ encW1, const float* __restrict__ encb1,
    const float* __restrict__ encW2, const float* __restrict__ encb2,
    const float* __restrict__ Wih,
    const float* __restrict__ bih,  const float* __restrict__ bhh,
    const unsigned short* __restrict__ Wph,
    float* __restrict__ esum)
{
    __shared__ char pool[98304];           // B ring (8 waves x 3 x 4KB); sbuf aliased
    __shared__ short hhi[2][16 * 256];     // 8 KB x2, XOR-swizzled cols
    __shared__ short hlo[2][16 * 256];

    float* sbuf = (float*)pool;            // setup scratch (33792 B <= ring)

    const int tid   = threadIdx.x;
    const int j     = tid & 255;
    const int rh    = tid >> 8;
    const int rbase = rh * 8;
    const int r0    = blockIdx.x * 16;

    // ==================== setup (f32, one-time) ====================
    {
        float acc[8];
        float b = encb1[j];
        #pragma unroll
        for (int r = 0; r < 8; ++r) acc[r] = b;
        for (int k = 0; k < N_FEAT; ++k) {
            float w = encW1[k * NHID + j];
            #pragma unroll
            for (int r = 0; r < 8; ++r)
                acc[r] = fmaf(ctx[(r0 + rbase + r) * N_FEAT + k], w, acc[r]);
        }
        #pragma unroll
        for (int r = 0; r < 8; ++r)
            sbuf[(rbase + r) * SSTR + j] = fmaxf(acc[r], 0.0f);
    }
    __syncthreads();

    {
        float p[8];
        float b = encb2[j];
        #pragma unroll
        for (int r = 0; r < 8; ++r) p[r] = b;
        for (int k = 0; k < NHID; ++k) {
            float w = encW2[k * ENC + j];
            #pragma unroll
            for (int r = 0; r < 8; ++r)
                p[r] = fmaf(sbuf[(rbase + r) * SSTR + k], w, p[r]);
        }
        __syncthreads();
        #pragma unroll
        for (int r = 0; r < 8; ++r)
            sbuf[(rbase + r) * SSTR + 264 + j] = p[r];
    }
    __syncthreads();

    float xp[4][8];
    #pragma unroll
    for (int g = 0; g < 4; ++g) {
        int m = g * 256 + j;
        float b = bih[m] + bhh[m];
        #pragma unroll
        for (int r = 0; r < 8; ++r) xp[g][r] = b;
        const float4* wrow = (const float4*)(Wih + m * ENC);
        for (int k4 = 0; k4 < ENC / 4; ++k4) {
            float4 wv = wrow[k4];
            #pragma unroll
            for (int r = 0; r < 8; ++r) {
                const float* ph = &sbuf[(rbase + r) * SSTR + 264 + k4 * 4];
                float v = xp[g][r];
                v = fmaf(ph[0], wv.x, v);
                v = fmaf(ph[1], wv.y, v);
                v = fmaf(ph[2], wv.z, v);
                v = fmaf(ph[3], wv.w, v);
                xp[g][r] = v;
            }
        }
    }
    __syncthreads();

    const int w    = tid >> 6;        // wave 0..7
    const int l    = tid & 63;
    const int col  = l & 15;          // C col / A row
    const int kp   = l >> 4;          // 0..3
    const int arow = col;
    const int asw  = (arow & 7) << 3; // short-unit XOR swizzle

    // xp -> C-fragment layout (one gate at a time through sbuf)
    f32x4 xpf[4][2];
    #pragma unroll 1
    for (int g = 0; g < 4; ++g) {
        #pragma unroll
        for (int r = 0; r < 8; ++r)
            sbuf[(rbase + r) * SSTR + j] = xp[g][r];
        __syncthreads();
        #pragma unroll
        for (int u = 0; u < 2; ++u)
            #pragma unroll
            for (int q = 0; q < 4; ++q)
                xpf[g][u][q] = sbuf[(kp * 4 + q) * SSTR + w * 32 + u * 16 + col];
        __syncthreads();
    }

    for (int i = tid; i < 16 * 256; i += 512) { hhi[0][i] = 0; hlo[0][i] = 0; }
    __syncthreads();   // setup done; pool becomes the B ring from here on

    const unsigned short* Bh = Wph + (size_t)l * 8;
    char* ra = pool + (w * 3 + 0) * 4096;
    char* rb = pool + (w * 3 + 1) * 4096;
    char* rc = pool + (w * 3 + 2) * 4096;
    const size_t lane16 = (size_t)l * 16;

// issue group gj (0..15: u = gj>>3, ks = gj&7) into ring slot base
#define ISSUE(base, gj) do {                                                 \
        const int u_ = (gj) >> 3, ks2_ = (gj) & 7;                           \
        _Pragma("unroll") for (int g_ = 0; g_ < 4; ++g_) {                   \
            const unsigned short* gp_ = Bh +                                 \
                (size_t)(((16 * g_ + 2 * w + u_) * 8 + ks2_) * 64) * 8;      \
            async16(gp_, (base) + g_ * 1024);                                \
        }                                                                    \
    } while (0)

// consume group gi from slot base (8 MFMAs), then refill it with gi+3 (mod 16)
#define CNS(base, gi) do {                                                   \
        asm volatile("s_waitcnt vmcnt(8)" ::: "memory");                     \
        __builtin_amdgcn_sched_barrier(0);                                   \
        const char* p_ = (base) + lane16;                                    \
        bf16x8 f0 = *(const bf16x8*)(p_);                                    \
        bf16x8 f1 = *(const bf16x8*)(p_ + 1024);                             \
        bf16x8 f2 = *(const bf16x8*)(p_ + 2048);                             \
        bf16x8 f3 = *(const bf16x8*)(p_ + 3072);                             \
        const int ks_ = (gi) & 7;                                            \
        bf16x8 ah = *(const bf16x8*)&Ahi[arow * 256 +                        \
                        ((ks_ * 32 + kp * 8) ^ asw)];                        \
        bf16x8 al = *(const bf16x8*)&Alo[arow * 256 +                        \
                        ((ks_ * 32 + kp * 8) ^ asw)];                        \
        acc[0] = BMFMA(al, f0, acc[0]); acc[0] = BMFMA(ah, f0, acc[0]);      \
        acc[1] = BMFMA(al, f1, acc[1]); acc[1] = BMFMA(ah, f1, acc[1]);      \
        acc[2] = BMFMA(al, f2, acc[2]); acc[2] = BMFMA(ah, f2, acc[2]);      \
        acc[3] = BMFMA(al, f3, acc[3]); acc[3] = BMFMA(ah, f3, acc[3]);      \
        asm volatile("" ::: "memory");                                       \
        ISSUE(base, ((gi) + 3) & 15);                                        \
    } while (0)

#define POINTW(u_) do {                                                      \
        float s = 0.0f;                                                      \
        _Pragma("unroll") for (int q = 0; q < 4; ++q) {                      \
            float iv = sigmoidf_(acc[0][q]);                                 \
            float fv = sigmoidf_(acc[1][q]);                                 \
            float gv = tanhf_   (acc[2][q]);                                 \
            float ov = sigmoidf_(acc[3][q]);                                 \
            c[u_][q] = fv * c[u_][q] + iv * gv;                              \
            float hv = ov * tanhf_(c[u_][q]);                                \
            s += hv;                                                         \
            unsigned short h16 = f2bf_rne(hv);                               \
            float lof = hv - bf2f(h16);                                      \
            int row  = kp * 4 + q;                                           \
            int hcol = w * 32 + (u_) * 16 + col;                             \
            int sidx = row * 256 + (hcol ^ ((row & 7) << 3));                \
            Nhi[sidx] = (short)h16;                                          \
            Nlo[sidx] = (short)f2bf_rne(lof);                                \
        }                                                                    \
        su[u_] = s;                                                          \
    } while (0)

    // prologue: 3 groups in flight
    ISSUE(ra, 0); ISSUE(rb, 1); ISSUE(rc, 2);

    float c[2][4];
    #pragma unroll
    for (int u = 0; u < 2; ++u)
        #pragma unroll
        for (int q = 0; q < 4; ++q) c[u][q] = 0.0f;

    for (int t = 0; t < TSTEPS; ++t) {
        const short* Ahi = hhi[t & 1];
        const short* Alo = hlo[t & 1];
        short* Nhi = hhi[(t + 1) & 1];
        short* Nlo = hlo[(t + 1) & 1];

        float su[2];
        f32x4 acc[4];

        // ---- u = 0 ----
        #pragma unroll
        for (int g = 0; g < 4; ++g) acc[g] = xpf[g][0];
        CNS(ra, 0); CNS(rb, 1); CNS(rc, 2); CNS(ra, 3);
        CNS(rb, 4); CNS(rc, 5); CNS(ra, 6); CNS(rb, 7);
        POINTW(0);                       // VALU hides under in-flight loads

        // ---- u = 1 ----
        #pragma unroll
        for (int g = 0; g < 4; ++g) acc[g] = xpf[g][1];
        CNS(rc, 8);  CNS(ra, 9);  CNS(rb, 10); CNS(rc, 11);
        CNS(ra, 12); CNS(rb, 13); CNS(rc, 14); CNS(ra, 15);
        POINTW(1);

        #pragma unroll
        for (int u = 0; u < 2; ++u) {
            float v = su[u];
            v += __shfl_xor(v, 16);
            v += __shfl_xor(v, 32);
            if (l < 16)
                atomicAdd(&esum[t * GH + w * 32 + u * 16 + l], v);
        }

        // raw barrier: flush LDS ops only; keep global_load_lds in flight
        asm volatile("s_waitcnt lgkmcnt(0)" ::: "memory");
        __builtin_amdgcn_s_barrier();
        __builtin_amdgcn_sched_barrier(0);
        asm volatile("" ::: "memory");

        // rotate ring (next step's groups 0,1,2 already landing in rb,rc,ra)
        char* tp = ra; ra = rb; rb = rc; rc = tp;
    }
#undef ISSUE
#undef CNS
#undef POINTW
}

// ---------------------------------------------------------------------------
// Kernel C: proj[t][c] = (esum[t]/4096) @ W1_h + att_b1[c]
// ---------------------------------------------------------------------------
__global__ void proj_kernel(const float* __restrict__ esum,
                            const float* __restrict__ attW1,
                            const float* __restrict__ attb1,
                            float* __restrict__ proj)
{
    __shared__ float part[4][AH];
    const int t   = blockIdx.x;
    const int cix = threadIdx.x & 63;
    const int g   = threadIdx.x >> 6;
    float a = 0.0f;
    #pragma unroll 4
    for (int k = g * 64; k < g * 64 + 64; ++k) {
        float e = esum[t * GH + k] * (1.0f / (float)N_TRAIN);
        a = fmaf(e, attW1[(size_t)(N_TRAIN + k) * AH + cix], a);
    }
    part[g][cix] = a;
    __syncthreads();
    if (threadIdx.x < AH)
        proj[t * AH + cix] = part[0][cix] + part[1][cix] + part[2][cix] +
                             part[3][cix] + attb1[cix];
}

// ---------------------------------------------------------------------------
// Kernel D: S_proj via MFMA (4-term bf16 hi/lo split), fused scores epilogue.
// (unchanged from round 10)
// ---------------------------------------------------------------------------
__global__ __launch_bounds__(512, 4) void scores_kernel(
    const float* __restrict__ S,
    const unsigned short* __restrict__ Wah,
    const unsigned short* __restrict__ Wal,
    const float* __restrict__ proj,
    const float* __restrict__ attw2,
    const float* __restrict__ attb2,
    float* __restrict__ out)
{
    __shared__ float projl[TSTEPS * AH]; // 8 KB
    __shared__ float w2l[AH];

    const int tid   = threadIdx.x;
    const int wv    = tid >> 6;          // 0..7: ante-tile
    const int l     = tid & 63;
    const int kp    = l >> 4;            // 0..3
    const int atile = blockIdx.x * 128 + wv * 16;
    const int an    = atile + (l & 15);  // this lane's A-row (ante)

    f32x4 acc[4];
    #pragma unroll
    for (int ct = 0; ct < 4; ++ct) acc[ct] = (f32x4){0.f, 0.f, 0.f, 0.f};

    const float* Sp = S + an;
    const unsigned short* Bh = Wah + (size_t)l * 8;
    const unsigned short* Bl = Wal + (size_t)l * 8;

#define LOADS(dst, ks_) do {                                                 \
        _Pragma("unroll") for (int jj = 0; jj < 8; ++jj)                     \
            dst[jj] = Sp[(size_t)(32 * (ks_) + kp * 8 + jj) * NANTES];       \
    } while (0)

    float sA[8], sB[8];
    LOADS(sA, 0);
    LOADS(sB, 1);

    #pragma unroll 2
    for (int ks = 0; ks < 128; ++ks) {
        bf16x8 bh[4], bl[4];
        #pragma unroll
        for (int ct = 0; ct < 4; ++ct) {
            size_t off = (size_t)((ct * 128 + ks) * 64) * 8;
            bh[ct] = *(const bf16x8*)(Bh + off);
            bl[ct] = *(const bf16x8*)(Bl + off);
        }

        float* cur = (ks & 1) ? sB : sA;
        bf16x8 ah, al;
        #pragma unroll
        for (int jj = 0; jj < 8; ++jj) {
            float x = cur[jj];
            unsigned short h16 = f2bf_rne(x);
            ah[jj] = (short)h16;
            al[jj] = (short)f2bf_rne(x - bf2f(h16));
        }

        if (ks < 126) LOADS(cur, ks + 2);

        #pragma unroll
        for (int ct = 0; ct < 4; ++ct) {
            acc[ct] = BMFMA(al, bl[ct], acc[ct]);
            acc[ct] = BMFMA(al, bh[ct], acc[ct]);
            acc[ct] = BMFMA(ah, bl[ct], acc[ct]);
            acc[ct] = BMFMA(ah, bh[ct], acc[ct]);
        }
    }
#undef LOADS

    // ---- epilogue ----
    for (int i = tid; i < TSTEPS * AH; i += 512) projl[i] = proj[i];
    if (tid < AH) w2l[tid] = attw2[tid];
    __syncthreads();

    const float b2v = attb2[0];
    const int cn = l & 15;               // C col within tile
    #pragma unroll 1
    for (int t = 0; t < TSTEPS; ++t) {
        #pragma unroll
        for (int q = 0; q < 4; ++q) {
            float sc = 0.0f;
            #pragma unroll
            for (int ct = 0; ct < 4; ++ct) {
                int colg = ct * 16 + cn;
                sc += fmaxf(acc[ct][q] + projl[t * AH + colg], 0.0f) * w2l[colg];
            }
            sc += __shfl_xor(sc, 1);
            sc += __shfl_xor(sc, 2);
            sc += __shfl_xor(sc, 4);
            sc += __shfl_xor(sc, 8);
            if (cn == 0)
                out[(size_t)t * NANTES + atile + kp * 4 + q] = sc + b2v;
        }
    }
}

// ---------------------------------------------------------------------------
// Kernel E: per-step argmax (first-max semantics).
// ---------------------------------------------------------------------------
__global__ void argmax_kernel(const float* __restrict__ scores,
                              float* __restrict__ out)
{
    __shared__ float bv[256];
    __shared__ int   bidx[256];
    const int t = blockIdx.x, tid = threadIdx.x;
    float best = -INFINITY;
    int   bi   = 0x7fffffff;
    for (int a = tid; a < NANTES; a += 256) {
        float v = scores[(size_t)t * NANTES + a];
        if (v > best) { best = v; bi = a; }
    }
    bv[tid] = best; bidx[tid] = bi;
    __syncthreads();
    for (int s = 128; s > 0; s >>= 1) {
        if (tid < s) {
            if (bv[tid + s] > bv[tid] ||
                (bv[tid + s] == bv[tid] && bidx[tid + s] < bidx[tid])) {
                bv[tid] = bv[tid + s];
                bidx[tid] = bidx[tid + s];
            }
        }
        __syncthreads();
    }
    if (tid == 0)
        out[(size_t)TSTEPS * NANTES + t] = (float)bidx[0];
}

// ---------------------------------------------------------------------------
extern "C" void kernel_launch(void* const* d_in, const int* in_sizes, int n_in,
                              void* d_out, int out_size, void* d_ws, size_t ws_size,
                              hipStream_t stream)
{
    const float* ctx   = (const float*)d_in[0];
    const float* S     = (const float*)d_in[1];
    const float* encW1 = (const float*)d_in[2];
    const float* encb1 = (const float*)d_in[3];
    const float* encW2 = (const float*)d_in[4];
    const float* encb2 = (const float*)d_in[5];
    const float* Wih   = (const float*)d_in[6];
    const float* Whh   = (const float*)d_in[7];
    const float* bih   = (const float*)d_in[8];
    const float* bhh   = (const float*)d_in[9];
    const float* attW1 = (const float*)d_in[10];
    const float* attb1 = (const float*)d_in[11];
    const float* attw2 = (const float*)d_in[12];
    const float* attb2 = (const float*)d_in[13];

    char* ws = (char*)d_ws;
    float* esum = (float*)ws;                                     // 32 KB
    float* proj = (float*)(ws + 32768);                           // 8 KB
    unsigned short* Wph = (unsigned short*)(ws + 40960);          // 512 KB
    unsigned short* Wah = (unsigned short*)(ws + 40960 + 524288); // 512 KB
    unsigned short* Wal = (unsigned short*)(ws + 40960 + 1048576);// 512 KB
    float* out  = (float*)d_out;

    zero_kernel<<<dim3(8), dim3(256), 0, stream>>>(esum);
    pack_whh<<<dim3(128), dim3(256), 0, stream>>>(Whh, Wph);
    pack_wa<<<dim3(128), dim3(256), 0, stream>>>(attW1, Wah, Wal);
    lstm_kernel<<<dim3(N_TRAIN / 16), dim3(512), 0, stream>>>(
        ctx, encW1, encb1, encW2, encb2, Wih, bih, bhh, Wph, esum);
    proj_kernel<<<dim3(TSTEPS), dim3(256), 0, stream>>>(esum, attW1, attb1, proj);
    scores_kernel<<<dim3(NANTES / 128), dim3(512), 0, stream>>>(
        S, Wah, Wal, proj, attw2, attb2, out);
    argmax_kernel<<<dim3(TSTEPS), dim3(256), 0, stream>>>(out, out);
}